// Round 3
// baseline (746.539 us; speedup 1.0000x reference)
//
#include <hip/hip_runtime.h>

#define T_TOK 4096
#define DM 1024
#define DF 4096
#define NE 8
#define BM 128
#define BK 64
#define RCAP 9216   // 8192 + 8*128 worst-case padding
#define MAXT 72     // RCAP / BM
#define CHUNK_B 8192    // 64x64 fp16 swizzled chunk
#define ACH_B 16384     // 128x64 fp16 swizzled chunk

typedef _Float16 f16x8 __attribute__((ext_vector_type(8)));
typedef float f32x4 __attribute__((ext_vector_type(4)));

#define MFMA16(a, b, c) __builtin_amdgcn_mfma_f32_16x16x32_f16(a, b, c, 0, 0, 0)

__device__ __forceinline__ ushort f2h_bits(float f) {
    _Float16 h = (_Float16)f;
    return __builtin_bit_cast(unsigned short, h);
}

__device__ __forceinline__ uint4 pack8(float4 a, float4 b) {
    union { ushort u[8]; uint4 v; } r;
    r.u[0] = f2h_bits(a.x); r.u[1] = f2h_bits(a.y);
    r.u[2] = f2h_bits(a.z); r.u[3] = f2h_bits(a.w);
    r.u[4] = f2h_bits(b.x); r.u[5] = f2h_bits(b.y);
    r.u[6] = f2h_bits(b.z); r.u[7] = f2h_bits(b.w);
    return r.v;
}

// async global->LDS, 16B per lane; lds ptr must be wave-uniform
__device__ __forceinline__ void gll16(const void* g, void* l) {
    __builtin_amdgcn_global_load_lds(
        (const __attribute__((address_space(1))) unsigned int*)g,
        (__attribute__((address_space(3))) unsigned int*)l, 16, 0, 0);
}

// ---------------- init ----------------
__global__ __launch_bounds__(256) void k_init(float* __restrict__ out,
                                              int* __restrict__ misc,
                                              int* __restrict__ row_tok) {
    int i = blockIdx.x * 256 + threadIdx.x;
    if (i < T_TOK * DM + 1) out[i] = 0.f;
    if (i < RCAP) row_tok[i] = -1;
    if (i < 256) misc[i] = 0;   // cnt[8], fill[8], poff[8], texp[72]
}

// ---------------- router ----------------
__global__ __launch_bounds__(64) void k_router(const float* __restrict__ x,
                                               const float* __restrict__ Wr,
                                               float* __restrict__ probs,
                                               int* __restrict__ topi,
                                               float* __restrict__ topw,
                                               int* __restrict__ cnt) {
    int t = blockIdx.x;
    int lane = threadIdx.x;
    const float* xr = x + (size_t)t * DM;
    float s[NE];
#pragma unroll
    for (int e = 0; e < NE; e++) s[e] = 0.f;
    for (int j = lane; j < DM; j += 64) {
        float xv = xr[j];
#pragma unroll
        for (int e = 0; e < NE; e++) s[e] += xv * Wr[e * DM + j];
    }
#pragma unroll
    for (int off = 32; off > 0; off >>= 1) {
#pragma unroll
        for (int e = 0; e < NE; e++) s[e] += __shfl_xor(s[e], off, 64);
    }
    if (lane == 0) {
        float mx = s[0];
#pragma unroll
        for (int e = 1; e < NE; e++) mx = fmaxf(mx, s[e]);
        float ex[NE], sum = 0.f;
#pragma unroll
        for (int e = 0; e < NE; e++) { ex[e] = expf(s[e] - mx); sum += ex[e]; }
        float inv = 1.f / sum;
        float p[NE];
#pragma unroll
        for (int e = 0; e < NE; e++) { p[e] = ex[e] * inv; probs[t * NE + e] = p[e]; }
        int i0 = 0;
#pragma unroll
        for (int e = 1; e < NE; e++) if (p[e] > p[i0]) i0 = e;
        int i1 = (i0 == 0) ? 1 : 0;
#pragma unroll
        for (int e = 0; e < NE; e++) if (e != i0 && p[e] > p[i1]) i1 = e;
        float w0 = p[i0], w1 = p[i1], winv = 1.f / (w0 + w1);
        topi[2 * t] = i0;     topw[2 * t] = w0 * winv;
        topi[2 * t + 1] = i1; topw[2 * t + 1] = w1 * winv;
        atomicAdd(&cnt[i0], 1);
        atomicAdd(&cnt[i1], 1);
    }
}

// ---------------- scan ----------------
__global__ __launch_bounds__(256) void k_scan(const float* __restrict__ probs,
                                              const int* __restrict__ cnt,
                                              int* __restrict__ poff,
                                              int* __restrict__ texp,
                                              float* __restrict__ aux_out) {
    __shared__ float red[256 * NE];
    int tid = threadIdx.x;
    float part[NE];
#pragma unroll
    for (int e = 0; e < NE; e++) part[e] = 0.f;
    for (int t = tid; t < T_TOK; t += 256) {
#pragma unroll
        for (int e = 0; e < NE; e++) part[e] += probs[t * NE + e];
    }
#pragma unroll
    for (int e = 0; e < NE; e++) red[tid * NE + e] = part[e];
    __syncthreads();
    for (int s2 = 128; s2 > 0; s2 >>= 1) {
        if (tid < s2) {
#pragma unroll
            for (int e = 0; e < NE; e++) red[tid * NE + e] += red[(tid + s2) * NE + e];
        }
        __syncthreads();
    }
    if (tid == 0) {
        float al = 0.f;
#pragma unroll
        for (int e = 0; e < NE; e++) al += red[e] * (float)cnt[e];
        *aux_out = al * (8.0f / (16777216.0f + 1e-6f));
        int run = 0, tix = 0;
        for (int e = 0; e < NE; e++) {
            poff[e] = run;
            int nt = (cnt[e] + BM - 1) / BM;
            for (int i = 0; i < nt; i++) texp[tix++] = e;
            run += nt * BM;
        }
    }
}

// ---------------- assign ----------------
__global__ __launch_bounds__(256) void k_assign(const int* __restrict__ topi,
                                                const float* __restrict__ topw,
                                                const int* __restrict__ poff,
                                                int* __restrict__ fill,
                                                int* __restrict__ row_tok,
                                                float* __restrict__ row_w) {
    int t = blockIdx.x * 256 + threadIdx.x;
    if (t >= T_TOK) return;
#pragma unroll
    for (int k = 0; k < 2; k++) {
        int e = topi[2 * t + k];
        int pos = atomicAdd(&fill[e], 1);
        int r = poff[e] + pos;
        row_tok[r] = t;
        row_w[r] = topw[2 * t + k];
    }
}

// convert fp32 row-major [rows][row_len] -> tile-ordered swizzled fp16 chunks
// chunk (rt, kt) = 64x64, element (r,c) at byte r*128 + ((2c) ^ ((r&7)<<4))
__global__ __launch_bounds__(256) void k_convert(const float* __restrict__ src,
                                                 ushort* __restrict__ dst,
                                                 int row_len) {
    int nk = row_len >> 6;
    int kt = blockIdx.x, rt = blockIdx.y;
    int tid = threadIdx.x;
    int r = tid >> 2, c0 = (tid & 3) * 16;
    const float* s = src + (size_t)(rt * 64 + r) * row_len + kt * 64 + c0;
    float4 v0 = *(const float4*)(s);
    float4 v1 = *(const float4*)(s + 4);
    float4 v2 = *(const float4*)(s + 8);
    float4 v3 = *(const float4*)(s + 12);
    char* chunk = (char*)dst + ((size_t)rt * nk + kt) * CHUNK_B;
    int sw = (r & 7) << 4;
    *(uint4*)(chunk + r * 128 + ((2 * c0) ^ sw)) = pack8(v0, v1);
    *(uint4*)(chunk + r * 128 + ((2 * c0 + 16) ^ sw)) = pack8(v2, v3);
}

// gather x rows into tile-ordered swizzled fp16: chunk (rt, kt) = 128x64
__global__ __launch_bounds__(256) void k_gather_t(const float* __restrict__ x,
                                                  const int* __restrict__ row_tok,
                                                  ushort* __restrict__ xg) {
    int kt = blockIdx.x, rt = blockIdx.y;
    int tid = threadIdx.x;
    int r = tid >> 1, c0 = (tid & 1) * 32;
    int tok = row_tok[rt * BM + r];
    char* chunk = (char*)xg + ((size_t)rt * 16 + kt) * ACH_B;
    int sw = (r & 7) << 4;
    if (tok >= 0) {
        const float* s = x + (size_t)tok * DM + kt * 64 + c0;
#pragma unroll
        for (int j = 0; j < 4; j++) {
            float4 va = *(const float4*)(s + j * 8);
            float4 vb = *(const float4*)(s + j * 8 + 4);
            *(uint4*)(chunk + r * 128 + ((2 * (c0 + j * 8)) ^ sw)) = pack8(va, vb);
        }
    } else {
        uint4 z = {0, 0, 0, 0};
#pragma unroll
        for (int j = 0; j < 4; j++)
            *(uint4*)(chunk + r * 128 + ((2 * (c0 + j * 8)) ^ sw)) = z;
    }
}

// GEMM1: h = silu(xg @ W1^T) * (xg @ W3^T); 2-phase double-buffered
__global__ __launch_bounds__(256) void k_gemm1_t(const ushort* __restrict__ xg,
                                                 const ushort* __restrict__ W1h,
                                                 const ushort* __restrict__ W3h,
                                                 const int* __restrict__ texp,
                                                 ushort* __restrict__ hbuf) {
    __shared__ __align__(16) char lA[2][16384];
    __shared__ __align__(16) char lB1[2][8192];
    __shared__ __align__(16) char lB3[2][8192];
    int ct = blockIdx.x, rt = blockIdx.y;
    int e = texp[rt];
    const char* Ac  = (const char*)xg + (size_t)rt * 16 * ACH_B;
    const char* B1c = (const char*)W1h + (size_t)((e * 64 + ct) * 16) * CHUNK_B;
    const char* B3c = (const char*)W3h + (size_t)((e * 64 + ct) * 16) * CHUNK_B;
    int tid = threadIdx.x, lane = tid & 63, wv = tid >> 6;
    int wr = wv >> 1, wc = wv & 1;

    const f32x4 fz = {0.f, 0.f, 0.f, 0.f};
    f32x4 acc1[4][2], acc3[4][2];
#pragma unroll
    for (int m = 0; m < 4; m++)
#pragma unroll
        for (int n = 0; n < 2; n++) { acc1[m][n] = fz; acc3[m][n] = fz; }

#define G1_STAGE(kt_, b_)                                                              \
    {                                                                                  \
        const char* As_  = Ac + (kt_) * ACH_B;                                         \
        const char* B1s_ = B1c + (kt_) * CHUNK_B;                                      \
        const char* B3s_ = B3c + (kt_) * CHUNK_B;                                      \
        _Pragma("unroll")                                                              \
        for (int i = 0; i < 4; i++)                                                    \
            gll16(As_ + wv * 4096 + i * 1024 + lane * 16, lA[b_] + wv * 4096 + i * 1024); \
        _Pragma("unroll")                                                              \
        for (int i = 0; i < 2; i++)                                                    \
            gll16(B1s_ + wv * 2048 + i * 1024 + lane * 16, lB1[b_] + wv * 2048 + i * 1024); \
        _Pragma("unroll")                                                              \
        for (int i = 0; i < 2; i++)                                                    \
            gll16(B3s_ + wv * 2048 + i * 1024 + lane * 16, lB3[b_] + wv * 2048 + i * 1024); \
    }

    G1_STAGE(0, 0);
    asm volatile("s_waitcnt vmcnt(0)" ::: "memory");
    __syncthreads();
    int cur = 0;
    for (int kt = 0; kt < 16; kt++) {
        if (kt < 15) G1_STAGE(kt + 1, cur ^ 1);
#pragma unroll
        for (int ks = 0; ks < 2; ks++) {
            int kbyte = (ks * 32 + (lane >> 4) * 8) * 2;
            f16x8 af[4];
#pragma unroll
            for (int m = 0; m < 4; m++) {
                int r = wr * 64 + m * 16 + (lane & 15);
                af[m] = *(const f16x8*)(lA[cur] + r * 128 + (kbyte ^ ((r & 7) << 4)));
            }
#pragma unroll
            for (int n = 0; n < 2; n++) {
                int c = wc * 32 + n * 16 + (lane & 15);
                int off = c * 128 + (kbyte ^ ((c & 7) << 4));
                f16x8 b1 = *(const f16x8*)(lB1[cur] + off);
                f16x8 b3 = *(const f16x8*)(lB3[cur] + off);
#pragma unroll
                for (int m = 0; m < 4; m++) {
                    acc1[m][n] = MFMA16(af[m], b1, acc1[m][n]);
                    acc3[m][n] = MFMA16(af[m], b3, acc3[m][n]);
                }
            }
        }
        asm volatile("s_waitcnt vmcnt(0)" ::: "memory");
        __syncthreads();
        cur ^= 1;
    }
#undef G1_STAGE
    // epilogue: silu -> hbuf chunk (rt, ct) in gemm2 A-tile order, swizzled
    char* hc = (char*)hbuf + (size_t)(rt * 64 + ct) * ACH_B;
#pragma unroll
    for (int m = 0; m < 4; m++) {
#pragma unroll
        for (int i = 0; i < 4; i++) {
            int r = wr * 64 + m * 16 + (lane >> 4) * 4 + i;
            int sw = (r & 7) << 4;
#pragma unroll
            for (int n = 0; n < 2; n++) {
                int f = wc * 32 + n * 16 + (lane & 15);
                float a1 = acc1[m][n][i], a3 = acc3[m][n][i];
                float h = (a1 / (1.f + expf(-a1))) * a3;
                *(ushort*)(hc + r * 128 + ((2 * f) ^ sw)) = f2h_bits(h);
            }
        }
    }
}

// GEMM2: y = h @ W2^T; 128x64 tile, 2-phase double-buffered, atomic scatter
__global__ __launch_bounds__(256) void k_gemm2_t(const ushort* __restrict__ hbuf,
                                                 const ushort* __restrict__ W2h,
                                                 const int* __restrict__ texp,
                                                 const int* __restrict__ row_tok,
                                                 const float* __restrict__ row_w,
                                                 float* __restrict__ out) {
    __shared__ __align__(16) char lA[2][16384];
    __shared__ __align__(16) char lB[2][8192];
    int ct = blockIdx.x, rt = blockIdx.y;   // ct in [0,16)
    int e = texp[rt];
    const char* Ac = (const char*)hbuf + (size_t)rt * 64 * ACH_B;
    const char* Bc = (const char*)W2h + (size_t)((e * 16 + ct) * 64) * CHUNK_B;
    int tid = threadIdx.x, lane = tid & 63, wv = tid >> 6;
    int wr = wv >> 1, wc = wv & 1;

    const f32x4 fz = {0.f, 0.f, 0.f, 0.f};
    f32x4 acc[4][2];
#pragma unroll
    for (int m = 0; m < 4; m++)
#pragma unroll
        for (int n = 0; n < 2; n++) acc[m][n] = fz;

#define G2_STAGE(kt_, b_)                                                              \
    {                                                                                  \
        const char* As_ = Ac + (kt_) * ACH_B;                                          \
        const char* Bs_ = Bc + (kt_) * CHUNK_B;                                        \
        _Pragma("unroll")                                                              \
        for (int i = 0; i < 4; i++)                                                    \
            gll16(As_ + wv * 4096 + i * 1024 + lane * 16, lA[b_] + wv * 4096 + i * 1024); \
        _Pragma("unroll")                                                              \
        for (int i = 0; i < 2; i++)                                                    \
            gll16(Bs_ + wv * 2048 + i * 1024 + lane * 16, lB[b_] + wv * 2048 + i * 1024); \
    }

    G2_STAGE(0, 0);
    asm volatile("s_waitcnt vmcnt(0)" ::: "memory");
    __syncthreads();
    int cur = 0;
    for (int kt = 0; kt < 64; kt++) {
        if (kt < 63) G2_STAGE(kt + 1, cur ^ 1);
#pragma unroll
        for (int ks = 0; ks < 2; ks++) {
            int kbyte = (ks * 32 + (lane >> 4) * 8) * 2;
            f16x8 af[4];
#pragma unroll
            for (int m = 0; m < 4; m++) {
                int r = wr * 64 + m * 16 + (lane & 15);
                af[m] = *(const f16x8*)(lA[cur] + r * 128 + (kbyte ^ ((r & 7) << 4)));
            }
#pragma unroll
            for (int n = 0; n < 2; n++) {
                int c = wc * 32 + n * 16 + (lane & 15);
                f16x8 b = *(const f16x8*)(lB[cur] + c * 128 + (kbyte ^ ((c & 7) << 4)));
#pragma unroll
                for (int m = 0; m < 4; m++) acc[m][n] = MFMA16(af[m], b, acc[m][n]);
            }
        }
        asm volatile("s_waitcnt vmcnt(0)" ::: "memory");
        __syncthreads();
        cur ^= 1;
    }
#undef G2_STAGE
    // epilogue: out[tok] += w * y (exactly 2 commutative adds per element)
    int cbase = ct * 64 + wc * 32;
#pragma unroll
    for (int m = 0; m < 4; m++) {
#pragma unroll
        for (int i = 0; i < 4; i++) {
            int rr = rt * BM + wr * 64 + m * 16 + (lane >> 4) * 4 + i;
            int tok = row_tok[rr];
            if (tok >= 0) {
                float w = row_w[rr];
                float* orow = out + (size_t)tok * DM + cbase + (lane & 15);
#pragma unroll
                for (int n = 0; n < 2; n++) atomicAdd(&orow[n * 16], w * acc[m][n][i]);
            }
        }
    }
}

extern "C" void kernel_launch(void* const* d_in, const int* in_sizes, int n_in,
                              void* d_out, int out_size, void* d_ws, size_t ws_size,
                              hipStream_t stream) {
    (void)in_sizes; (void)n_in; (void)out_size; (void)ws_size;
    const float* x  = (const float*)d_in[0];
    const float* Wr = (const float*)d_in[1];
    const float* W1 = (const float*)d_in[2];
    const float* W2 = (const float*)d_in[3];
    const float* W3 = (const float*)d_in[4];
    float* out = (float*)d_out;
    char* ws = (char*)d_ws;

    int* misc = (int*)ws;            // [cnt 8][fill 8][poff 8][texp 72]
    int* cnt  = misc;
    int* fill = misc + 8;
    int* poff = misc + 16;
    int* texp = misc + 24;
    int*    topi    = (int*)(ws + 1024);
    float*  topw    = (float*)(ws + 33792);
    float*  probs   = (float*)(ws + 66560);
    int*    row_tok = (int*)(ws + 197632);
    float*  row_w   = (float*)(ws + 234496);
    ushort* xg      = (ushort*)(ws + 271360);     // 18.9 MB
    ushort* hbuf    = (ushort*)(ws + 19145728);   // 75.5 MB
    ushort* W1h     = (ushort*)(ws + 94643200);   // 64 MB
    ushort* W3h     = (ushort*)(ws + 161752064);  // 64 MB
    ushort* W2h     = (ushort*)(ws + 228860928);  // 64 MB -> ends 295969792

    k_init<<<(T_TOK * DM + 1 + 255) / 256, 256, 0, stream>>>(out, misc, row_tok);
    k_router<<<T_TOK, 64, 0, stream>>>(x, Wr, probs, topi, topw, cnt);
    k_scan<<<1, 256, 0, stream>>>(probs, cnt, poff, texp, out + (size_t)T_TOK * DM);
    k_assign<<<(T_TOK + 255) / 256, 256, 0, stream>>>(topi, topw, poff, fill, row_tok, row_w);

    k_convert<<<dim3(16, 512), 256, 0, stream>>>(W1, W1h, DM);
    k_convert<<<dim3(16, 512), 256, 0, stream>>>(W3, W3h, DM);
    k_convert<<<dim3(64, 128), 256, 0, stream>>>(W2, W2h, DF);
    k_gather_t<<<dim3(16, MAXT), 256, 0, stream>>>(x, row_tok, xg);
    k_gemm1_t<<<dim3(64, MAXT), 256, 0, stream>>>(xg, W1h, W3h, texp, hbuf);
    k_gemm2_t<<<dim3(16, MAXT), 256, 0, stream>>>(hbuf, W2h, texp, row_tok, row_w, out);
}